// Round 1
// baseline (211.902 us; speedup 1.0000x reference)
//
#include <hip/hip_runtime.h>
#include <hip/hip_bf16.h>

#define HIDDEN   128
#define EDGE_DIM 32
#define NEDGE    800000
#define KSTEPS   9          // K = 288 = 9*32  (128 src + 128 dst + 32 edge_attr)
#define NFRAG    8          // 128 output cols / 16

typedef __attribute__((ext_vector_type(4))) float        f32x4;
typedef __attribute__((ext_vector_type(8))) short        bf16x8;
typedef __attribute__((ext_vector_type(4))) unsigned int u32x4;

#define BPACK_USHORTS  (KSTEPS * NFRAG * 64 * 8)   // 36864 bf16 = 73728 B
#define BIAS_OFF_BYTES (BPACK_USHORTS * 2)         // 73728
#define FLAG_OFF_BYTES (BIAS_OFF_BYTES + 128 * 4)  // 74240

__device__ __forceinline__ unsigned short f2bf(float f) {
  unsigned u = __builtin_bit_cast(unsigned, f);
  u += 0x7FFFu + ((u >> 16) & 1u);   // RNE
  return (unsigned short)(u >> 16);
}

// Setup: build folded, MFMA-fragment-packed B (bf16) + effective bias + idx-dtype flag.
// W_cat rows: [0,128) = W1[0:128] (src), [128,256) = W1[256:384] (dst),
//             [256,288) = W_edge @ W1[128:256] (edge_attr, MLP folded).
__global__ void setup_kernel(const float* __restrict__ W_edge,
                             const float* __restrict__ b_edge,
                             const float* __restrict__ W1,
                             const float* __restrict__ b1,
                             const void*  __restrict__ eidx,
                             unsigned short* __restrict__ Bpack,
                             float* __restrict__ bias_eff,
                             int*   __restrict__ flag64) {
  const int bid = blockIdx.x, tid = threadIdx.x;
  if (bid < 36) {
    const int pair  = bid * 2 + (tid >> 6);   // 0..71 = kstep*8 + nfrag
    const int lane  = tid & 63;
    const int kstep = pair >> 3;
    const int f     = pair & 7;
    const int col   = f * 16 + (lane & 15);
    const int kbase = kstep * 32 + (lane >> 4) * 8;
    float vals[8];
#pragma unroll
    for (int j = 0; j < 8; ++j) {
      const int k = kbase + j;
      float val;
      if (k < 128) {
        val = W1[k * 128 + col];
      } else if (k < 256) {
        val = W1[(k + 128) * 128 + col];
      } else {
        const int kk = k - 256;
        float s = 0.f;
        for (int t = 0; t < 128; ++t)
          s = fmaf(W_edge[kk * 128 + t], W1[(128 + t) * 128 + col], s);
        val = s;
      }
      vals[j] = val;
    }
    u32x4 sv;
#pragma unroll
    for (int j = 0; j < 4; ++j)
      sv[j] = (unsigned)f2bf(vals[2 * j]) | ((unsigned)f2bf(vals[2 * j + 1]) << 16);
    *(u32x4*)(Bpack + ((kstep * NFRAG + f) * 64 + lane) * 8) = sv;
  } else {
    if (tid < 128) {
      float s = b1[tid];
      for (int t = 0; t < 128; ++t)
        s = fmaf(b_edge[t], W1[(128 + t) * 128 + tid], s);
      bias_eff[tid] = s;
    }
    if (tid == 0) {
      // int64 detection: random indices < 50000 -> int64 view has all odd u32 words == 0
      const unsigned* w = (const unsigned*)eidx;
      int all0 = 1;
      for (int i = 0; i < 64; ++i) all0 &= (w[2 * i + 1] == 0u) ? 1 : 0;
      *flag64 = all0;
    }
  }
}

__device__ __forceinline__ unsigned cvt_pk_bf16(float a, float b) {
  union { __hip_bfloat162 h; unsigned u; } cv;
  cv.h = __float22bfloat162_rn(make_float2(a, b));   // v_cvt_pk_bf16_f32
  return cv.u;
}

__device__ __forceinline__ bf16x8 pack8(f32x4 lo, f32x4 hi) {
  u32x4 u;
  u[0] = cvt_pk_bf16(lo[0], lo[1]);
  u[1] = cvt_pk_bf16(lo[2], lo[3]);
  u[2] = cvt_pk_bf16(hi[0], hi[1]);
  u[3] = cvt_pk_bf16(hi[2], hi[3]);
  return __builtin_bit_cast(bf16x8, u);
}

// One wave = 32 edges (2 M-frags). No LDS, no barriers.
__global__ __launch_bounds__(256) void edge_attn_kernel(
    const float* __restrict__ nodef,
    const float* __restrict__ eattr,
    const void*  __restrict__ eidx,
    const unsigned short* __restrict__ Bpack,
    const float* __restrict__ bias_eff,
    const float* __restrict__ W2,
    const float* __restrict__ b2,
    const int*   __restrict__ flag64,
    float* __restrict__ out) {
  const int lane  = threadIdx.x & 63;
  const int wid   = threadIdx.x >> 6;
  const int ebase = blockIdx.x * 128 + wid * 32;
  const int l15   = lane & 15;
  const int kg    = lane >> 4;      // 0..3
  const int koff  = kg * 8;

  const int e0 = ebase + l15;
  const int e1 = e0 + 16;

  long r0, c0, r1, c1;
  if (*flag64) {
    const long long* p = (const long long*)eidx;
    r0 = (long)p[e0];          r1 = (long)p[e1];
    c0 = (long)p[NEDGE + e0];  c1 = (long)p[NEDGE + e1];
  } else {
    const int* p = (const int*)eidx;
    r0 = p[e0];          r1 = p[e1];
    c0 = p[NEDGE + e0];  c1 = p[NEDGE + e1];
  }

  f32x4 acc[2][NFRAG];
#pragma unroll
  for (int m = 0; m < 2; ++m)
#pragma unroll
    for (int f = 0; f < NFRAG; ++f)
      acc[m][f] = (f32x4){0.f, 0.f, 0.f, 0.f};

#pragma unroll 1
  for (int ks = 0; ks < KSTEPS; ++ks) {
    const float *p0, *p1;
    if (ks < 4)      { p0 = nodef + r0 * HIDDEN + ks * 32;       p1 = nodef + r1 * HIDDEN + ks * 32; }
    else if (ks < 8) { p0 = nodef + c0 * HIDDEN + (ks - 4) * 32; p1 = nodef + c1 * HIDDEN + (ks - 4) * 32; }
    else             { p0 = eattr + (long)e0 * EDGE_DIM;         p1 = eattr + (long)e1 * EDGE_DIM; }

    f32x4 lo0 = *(const f32x4*)(p0 + koff);
    f32x4 hi0 = *(const f32x4*)(p0 + koff + 4);
    f32x4 lo1 = *(const f32x4*)(p1 + koff);
    f32x4 hi1 = *(const f32x4*)(p1 + koff + 4);
    bf16x8 a0 = pack8(lo0, hi0);
    bf16x8 a1 = pack8(lo1, hi1);

#pragma unroll
    for (int f = 0; f < NFRAG; ++f) {
      bf16x8 bfr = *(const bf16x8*)(Bpack + ((ks * NFRAG + f) * 64 + lane) * 8);
      acc[0][f] = __builtin_amdgcn_mfma_f32_16x16x32_bf16(a0, bfr, acc[0][f], 0, 0, 0);
      acc[1][f] = __builtin_amdgcn_mfma_f32_16x16x32_bf16(a1, bfr, acc[1][f], 0, 0, 0);
    }
  }

  // Epilogue: bias + ReLU + dot(W2) in registers, 16-lane xor-reduce, sigmoid.
  float w2v[NFRAG], bv[NFRAG];
#pragma unroll
  for (int f = 0; f < NFRAG; ++f) {
    w2v[f] = W2[f * 16 + l15];
    bv[f]  = bias_eff[f * 16 + l15];
  }
  const float bias2 = b2[0];

  float part[2][4];
#pragma unroll
  for (int m = 0; m < 2; ++m)
#pragma unroll
    for (int r = 0; r < 4; ++r) {
      float s = 0.f;
#pragma unroll
      for (int f = 0; f < NFRAG; ++f) {
        float h = acc[m][f][r] + bv[f];
        h = fmaxf(h, 0.f);
        s = fmaf(h, w2v[f], s);
      }
      part[m][r] = s;
    }

#pragma unroll
  for (int mask = 1; mask < 16; mask <<= 1) {
#pragma unroll
    for (int m = 0; m < 2; ++m)
#pragma unroll
      for (int r = 0; r < 4; ++r)
        part[m][r] += __shfl_xor(part[m][r], mask, 64);
  }

  if (l15 == 0) {
#pragma unroll
    for (int m = 0; m < 2; ++m)
#pragma unroll
      for (int r = 0; r < 4; ++r) {
        float x = part[m][r] + bias2;
        out[ebase + m * 16 + kg * 4 + r] = 1.f / (1.f + __expf(-x));
      }
  }
}

extern "C" void kernel_launch(void* const* d_in, const int* in_sizes, int n_in,
                              void* d_out, int out_size, void* d_ws, size_t ws_size,
                              hipStream_t stream) {
  const float* nodef  = (const float*)d_in[0];
  const float* eattr  = (const float*)d_in[1];
  const float* W_edge = (const float*)d_in[2];
  const float* b_edge = (const float*)d_in[3];
  const float* W1     = (const float*)d_in[4];
  const float* b1     = (const float*)d_in[5];
  const float* W2     = (const float*)d_in[6];
  const float* b2     = (const float*)d_in[7];
  const void*  eidx   = d_in[8];

  unsigned short* Bpack    = (unsigned short*)d_ws;
  float*          bias_eff = (float*)((char*)d_ws + BIAS_OFF_BYTES);
  int*            flag64   = (int*)((char*)d_ws + FLAG_OFF_BYTES);

  setup_kernel<<<dim3(37), dim3(128), 0, stream>>>(W_edge, b_edge, W1, b1, eidx,
                                                   Bpack, bias_eff, flag64);

  edge_attn_kernel<<<dim3(NEDGE / 128), dim3(256), 0, stream>>>(
      nodef, eattr, eidx, Bpack, bias_eff, W2, b2, flag64, (float*)d_out);
}

// Round 2
// 207.156 us; speedup vs baseline: 1.0229x; 1.0229x over previous
//
#include <hip/hip_runtime.h>
#include <hip/hip_bf16.h>

#define HIDDEN   128
#define EDGE_DIM 32
#define NNODE    50000
#define NEDGE    800000
#define KSTEPS   9          // K = 288 = 9*32  (128 src + 128 dst + 32 edge_attr)
#define NFRAG    8          // 128 output cols / 16

typedef __attribute__((ext_vector_type(4))) float        f32x4;
typedef __attribute__((ext_vector_type(8))) short        bf16x8;
typedef __attribute__((ext_vector_type(4))) unsigned int u32x4;

#define BPACK_USHORTS  (KSTEPS * NFRAG * 64 * 8)   // 36864 bf16 = 73728 B
#define BIAS_OFF_BYTES (BPACK_USHORTS * 2)         // 73728
#define FLAG_OFF_BYTES (BIAS_OFF_BYTES + 128 * 4)  // 74240
#define NODE_OFF_BYTES 74752                       // 16B-aligned; bf16 nodes, 12.8 MB
#define WS_NEEDED      (NODE_OFF_BYTES + NNODE * HIDDEN * 2)

__device__ __forceinline__ unsigned short f2bf(float f) {
  unsigned u = __builtin_bit_cast(unsigned, f);
  u += 0x7FFFu + ((u >> 16) & 1u);   // RNE
  return (unsigned short)(u >> 16);
}

__device__ __forceinline__ unsigned cvt_pk_bf16(float a, float b) {
  union { __hip_bfloat162 h; unsigned u; } cv;
  cv.h = __float22bfloat162_rn(make_float2(a, b));   // v_cvt_pk_bf16_f32
  return cv.u;
}

__device__ __forceinline__ bf16x8 pack8(f32x4 lo, f32x4 hi) {
  u32x4 u;
  u[0] = cvt_pk_bf16(lo[0], lo[1]);
  u[1] = cvt_pk_bf16(lo[2], lo[3]);
  u[2] = cvt_pk_bf16(hi[0], hi[1]);
  u[3] = cvt_pk_bf16(hi[2], hi[3]);
  return __builtin_bit_cast(bf16x8, u);
}

// ---- setup 1: folded, fragment-packed B (bf16) + effective bias + idx dtype flag
__global__ void setup_kernel(const float* __restrict__ W_edge,
                             const float* __restrict__ b_edge,
                             const float* __restrict__ W1,
                             const float* __restrict__ b1,
                             const void*  __restrict__ eidx,
                             unsigned short* __restrict__ Bpack,
                             float* __restrict__ bias_eff,
                             int*   __restrict__ flag64) {
  const int bid = blockIdx.x, tid = threadIdx.x;
  if (bid < 36) {
    const int pair  = bid * 2 + (tid >> 6);   // 0..71 = kstep*8 + nfrag
    const int lane  = tid & 63;
    const int kstep = pair >> 3;
    const int f     = pair & 7;
    const int col   = f * 16 + (lane & 15);
    const int kbase = kstep * 32 + (lane >> 4) * 8;
    float vals[8];
#pragma unroll
    for (int j = 0; j < 8; ++j) {
      const int k = kbase + j;
      float val;
      if (k < 128) {
        val = W1[k * 128 + col];
      } else if (k < 256) {
        val = W1[(k + 128) * 128 + col];
      } else {
        const int kk = k - 256;
        float s = 0.f;
        for (int t = 0; t < 128; ++t)
          s = fmaf(W_edge[kk * 128 + t], W1[(128 + t) * 128 + col], s);
        val = s;
      }
      vals[j] = val;
    }
    u32x4 sv;
#pragma unroll
    for (int j = 0; j < 4; ++j)
      sv[j] = (unsigned)f2bf(vals[2 * j]) | ((unsigned)f2bf(vals[2 * j + 1]) << 16);
    *(u32x4*)(Bpack + ((kstep * NFRAG + f) * 64 + lane) * 8) = sv;
  } else {
    if (tid < 128) {
      float s = b1[tid];
      for (int t = 0; t < 128; ++t)
        s = fmaf(b_edge[t], W1[(128 + t) * 128 + tid], s);
      bias_eff[tid] = s;
    }
    if (tid == 0) {
      const unsigned* w = (const unsigned*)eidx;
      int all0 = 1;
      for (int i = 0; i < 64; ++i) all0 &= (w[2 * i + 1] == 0u) ? 1 : 0;
      *flag64 = all0;
    }
  }
}

// ---- setup 2: node_features fp32 -> bf16 (row-major, same layout)
__global__ __launch_bounds__(256) void cvt_nodes_kernel(const float* __restrict__ nodef,
                                                        unsigned short* __restrict__ nbf) {
  const int i = blockIdx.x * 256 + threadIdx.x;   // one 8-elem chunk per thread
  if (i >= NNODE * HIDDEN / 8) return;
  f32x4 lo = *(const f32x4*)(nodef + i * 8);
  f32x4 hi = *(const f32x4*)(nodef + i * 8 + 4);
  *(bf16x8*)(nbf + i * 8) = pack8(lo, hi);
}

// ---- main: one wave = 32 edges (2 M-frags), no LDS, no barriers.
// All node gathers issued up front (bf16, 1 load per row-slice).
__global__ __launch_bounds__(256, 3) void edge_attn_kernel(
    const unsigned short* __restrict__ nbf,
    const float* __restrict__ eattr,
    const void*  __restrict__ eidx,
    const unsigned short* __restrict__ Bpack,
    const float* __restrict__ bias_eff,
    const float* __restrict__ W2,
    const float* __restrict__ b2,
    const int*   __restrict__ flag64,
    float* __restrict__ out) {
  const int lane  = threadIdx.x & 63;
  const int wid   = threadIdx.x >> 6;
  const int ebase = blockIdx.x * 128 + wid * 32;
  const int l15   = lane & 15;
  const int kg    = lane >> 4;      // 0..3

  const int e0 = ebase + l15;
  const int e1 = e0 + 16;

  long r0, c0, r1, c1;
  if (*flag64) {
    const long long* p = (const long long*)eidx;
    r0 = (long)p[e0];          r1 = (long)p[e1];
    c0 = (long)p[NEDGE + e0];  c1 = (long)p[NEDGE + e1];
  } else {
    const int* p = (const int*)eidx;
    r0 = p[e0];          r1 = p[e1];
    c0 = p[NEDGE + e0];  c1 = p[NEDGE + e1];
  }

  const unsigned short* ps0 = nbf + (size_t)r0 * HIDDEN + kg * 8;
  const unsigned short* ps1 = nbf + (size_t)r1 * HIDDEN + kg * 8;
  const unsigned short* pd0 = nbf + (size_t)c0 * HIDDEN + kg * 8;
  const unsigned short* pd1 = nbf + (size_t)c1 * HIDDEN + kg * 8;

  // Issue all 16 node-gather loads up front (src + dst, both M-frags).
  bf16x8 as0[4], as1[4], ad0[4], ad1[4];
#pragma unroll
  for (int ks = 0; ks < 4; ++ks) {
    as0[ks] = *(const bf16x8*)(ps0 + ks * 32);
    as1[ks] = *(const bf16x8*)(ps1 + ks * 32);
  }
#pragma unroll
  for (int ks = 0; ks < 4; ++ks) {
    ad0[ks] = *(const bf16x8*)(pd0 + ks * 32);
    ad1[ks] = *(const bf16x8*)(pd1 + ks * 32);
  }

  f32x4 acc[2][NFRAG];
#pragma unroll
  for (int m = 0; m < 2; ++m)
#pragma unroll
    for (int f = 0; f < NFRAG; ++f)
      acc[m][f] = (f32x4){0.f, 0.f, 0.f, 0.f};

  // Phase 1: src rows, K-steps 0..3
#pragma unroll
  for (int ks = 0; ks < 4; ++ks) {
#pragma unroll
    for (int f = 0; f < NFRAG; ++f) {
      bf16x8 bfr = *(const bf16x8*)(Bpack + ((ks * NFRAG + f) * 64 + lane) * 8);
      acc[0][f] = __builtin_amdgcn_mfma_f32_16x16x32_bf16(as0[ks], bfr, acc[0][f], 0, 0, 0);
      acc[1][f] = __builtin_amdgcn_mfma_f32_16x16x32_bf16(as1[ks], bfr, acc[1][f], 0, 0, 0);
    }
  }

  // Issue edge_attr loads (fp32, streaming) while dst MFMAs run.
  const float* pe0 = eattr + (size_t)e0 * EDGE_DIM + kg * 8;
  const float* pe1 = eattr + (size_t)e1 * EDGE_DIM + kg * 8;
  f32x4 ea0lo = *(const f32x4*)(pe0);
  f32x4 ea0hi = *(const f32x4*)(pe0 + 4);
  f32x4 ea1lo = *(const f32x4*)(pe1);
  f32x4 ea1hi = *(const f32x4*)(pe1 + 4);

  // Phase 2: dst rows, K-steps 4..7
#pragma unroll
  for (int ks = 0; ks < 4; ++ks) {
#pragma unroll
    for (int f = 0; f < NFRAG; ++f) {
      bf16x8 bfr = *(const bf16x8*)(Bpack + (((ks + 4) * NFRAG + f) * 64 + lane) * 8);
      acc[0][f] = __builtin_amdgcn_mfma_f32_16x16x32_bf16(ad0[ks], bfr, acc[0][f], 0, 0, 0);
      acc[1][f] = __builtin_amdgcn_mfma_f32_16x16x32_bf16(ad1[ks], bfr, acc[1][f], 0, 0, 0);
    }
  }

  // Phase 3: edge_attr, K-step 8
  {
    bf16x8 ae0 = pack8(ea0lo, ea0hi);
    bf16x8 ae1 = pack8(ea1lo, ea1hi);
#pragma unroll
    for (int f = 0; f < NFRAG; ++f) {
      bf16x8 bfr = *(const bf16x8*)(Bpack + ((8 * NFRAG + f) * 64 + lane) * 8);
      acc[0][f] = __builtin_amdgcn_mfma_f32_16x16x32_bf16(ae0, bfr, acc[0][f], 0, 0, 0);
      acc[1][f] = __builtin_amdgcn_mfma_f32_16x16x32_bf16(ae1, bfr, acc[1][f], 0, 0, 0);
    }
  }

  // Epilogue: bias + ReLU + dot(W2) in registers, 16-lane xor-reduce, sigmoid.
  float w2v[NFRAG], bv[NFRAG];
#pragma unroll
  for (int f = 0; f < NFRAG; ++f) {
    w2v[f] = W2[f * 16 + l15];
    bv[f]  = bias_eff[f * 16 + l15];
  }
  const float bias2 = b2[0];

  float part[2][4];
#pragma unroll
  for (int m = 0; m < 2; ++m)
#pragma unroll
    for (int r = 0; r < 4; ++r) {
      float s = 0.f;
#pragma unroll
      for (int f = 0; f < NFRAG; ++f) {
        float h = acc[m][f][r] + bv[f];
        h = fmaxf(h, 0.f);
        s = fmaf(h, w2v[f], s);
      }
      part[m][r] = s;
    }

#pragma unroll
  for (int mask = 1; mask < 16; mask <<= 1) {
#pragma unroll
    for (int m = 0; m < 2; ++m)
#pragma unroll
      for (int r = 0; r < 4; ++r)
        part[m][r] += __shfl_xor(part[m][r], mask, 64);
  }

  if (l15 == 0) {
#pragma unroll
    for (int m = 0; m < 2; ++m)
#pragma unroll
      for (int r = 0; r < 4; ++r) {
        float x = part[m][r] + bias2;
        out[ebase + m * 16 + kg * 4 + r] = 1.f / (1.f + __expf(-x));
      }
  }
}

// ---- fallback main (round-1 style, fp32 gathers) in case ws is too small for bf16 nodes
__global__ __launch_bounds__(256) void edge_attn_kernel_fp32(
    const float* __restrict__ nodef,
    const float* __restrict__ eattr,
    const void*  __restrict__ eidx,
    const unsigned short* __restrict__ Bpack,
    const float* __restrict__ bias_eff,
    const float* __restrict__ W2,
    const float* __restrict__ b2,
    const int*   __restrict__ flag64,
    float* __restrict__ out) {
  const int lane  = threadIdx.x & 63;
  const int wid   = threadIdx.x >> 6;
  const int ebase = blockIdx.x * 128 + wid * 32;
  const int l15   = lane & 15;
  const int kg    = lane >> 4;
  const int koff  = kg * 8;
  const int e0 = ebase + l15;
  const int e1 = e0 + 16;

  long r0, c0, r1, c1;
  if (*flag64) {
    const long long* p = (const long long*)eidx;
    r0 = (long)p[e0];          r1 = (long)p[e1];
    c0 = (long)p[NEDGE + e0];  c1 = (long)p[NEDGE + e1];
  } else {
    const int* p = (const int*)eidx;
    r0 = p[e0];          r1 = p[e1];
    c0 = p[NEDGE + e0];  c1 = p[NEDGE + e1];
  }

  f32x4 acc[2][NFRAG];
#pragma unroll
  for (int m = 0; m < 2; ++m)
#pragma unroll
    for (int f = 0; f < NFRAG; ++f)
      acc[m][f] = (f32x4){0.f, 0.f, 0.f, 0.f};

#pragma unroll 1
  for (int ks = 0; ks < KSTEPS; ++ks) {
    const float *p0, *p1;
    if (ks < 4)      { p0 = nodef + r0 * HIDDEN + ks * 32;       p1 = nodef + r1 * HIDDEN + ks * 32; }
    else if (ks < 8) { p0 = nodef + c0 * HIDDEN + (ks - 4) * 32; p1 = nodef + c1 * HIDDEN + (ks - 4) * 32; }
    else             { p0 = eattr + (long)e0 * EDGE_DIM;         p1 = eattr + (long)e1 * EDGE_DIM; }

    f32x4 lo0 = *(const f32x4*)(p0 + koff);
    f32x4 hi0 = *(const f32x4*)(p0 + koff + 4);
    f32x4 lo1 = *(const f32x4*)(p1 + koff);
    f32x4 hi1 = *(const f32x4*)(p1 + koff + 4);
    bf16x8 a0 = pack8(lo0, hi0);
    bf16x8 a1 = pack8(lo1, hi1);

#pragma unroll
    for (int f = 0; f < NFRAG; ++f) {
      bf16x8 bfr = *(const bf16x8*)(Bpack + ((ks * NFRAG + f) * 64 + lane) * 8);
      acc[0][f] = __builtin_amdgcn_mfma_f32_16x16x32_bf16(a0, bfr, acc[0][f], 0, 0, 0);
      acc[1][f] = __builtin_amdgcn_mfma_f32_16x16x32_bf16(a1, bfr, acc[1][f], 0, 0, 0);
    }
  }

  float w2v[NFRAG], bv[NFRAG];
#pragma unroll
  for (int f = 0; f < NFRAG; ++f) {
    w2v[f] = W2[f * 16 + l15];
    bv[f]  = bias_eff[f * 16 + l15];
  }
  const float bias2 = b2[0];

  float part[2][4];
#pragma unroll
  for (int m = 0; m < 2; ++m)
#pragma unroll
    for (int r = 0; r < 4; ++r) {
      float s = 0.f;
#pragma unroll
      for (int f = 0; f < NFRAG; ++f) {
        float h = acc[m][f][r] + bv[f];
        h = fmaxf(h, 0.f);
        s = fmaf(h, w2v[f], s);
      }
      part[m][r] = s;
    }

#pragma unroll
  for (int mask = 1; mask < 16; mask <<= 1) {
#pragma unroll
    for (int m = 0; m < 2; ++m)
#pragma unroll
      for (int r = 0; r < 4; ++r)
        part[m][r] += __shfl_xor(part[m][r], mask, 64);
  }

  if (l15 == 0) {
#pragma unroll
    for (int m = 0; m < 2; ++m)
#pragma unroll
      for (int r = 0; r < 4; ++r) {
        float x = part[m][r] + bias2;
        out[ebase + m * 16 + kg * 4 + r] = 1.f / (1.f + __expf(-x));
      }
  }
}

extern "C" void kernel_launch(void* const* d_in, const int* in_sizes, int n_in,
                              void* d_out, int out_size, void* d_ws, size_t ws_size,
                              hipStream_t stream) {
  const float* nodef  = (const float*)d_in[0];
  const float* eattr  = (const float*)d_in[1];
  const float* W_edge = (const float*)d_in[2];
  const float* b_edge = (const float*)d_in[3];
  const float* W1     = (const float*)d_in[4];
  const float* b1     = (const float*)d_in[5];
  const float* W2     = (const float*)d_in[6];
  const float* b2     = (const float*)d_in[7];
  const void*  eidx   = d_in[8];

  unsigned short* Bpack    = (unsigned short*)d_ws;
  float*          bias_eff = (float*)((char*)d_ws + BIAS_OFF_BYTES);
  int*            flag64   = (int*)((char*)d_ws + FLAG_OFF_BYTES);
  unsigned short* nbf      = (unsigned short*)((char*)d_ws + NODE_OFF_BYTES);

  setup_kernel<<<dim3(37), dim3(128), 0, stream>>>(W_edge, b_edge, W1, b1, eidx,
                                                   Bpack, bias_eff, flag64);

  if (ws_size >= (size_t)WS_NEEDED) {
    cvt_nodes_kernel<<<dim3((NNODE * HIDDEN / 8 + 255) / 256), dim3(256), 0, stream>>>(nodef, nbf);
    edge_attn_kernel<<<dim3(NEDGE / 128), dim3(256), 0, stream>>>(
        nbf, eattr, eidx, Bpack, bias_eff, W2, b2, flag64, (float*)d_out);
  } else {
    edge_attn_kernel_fp32<<<dim3(NEDGE / 128), dim3(256), 0, stream>>>(
        nodef, eattr, eidx, Bpack, bias_eff, W2, b2, flag64, (float*)d_out);
  }
}

// Round 3
// 155.481 us; speedup vs baseline: 1.3629x; 1.3324x over previous
//
#include <hip/hip_runtime.h>
#include <hip/hip_bf16.h>

#define HIDDEN   128
#define EDGE_DIM 32
#define NNODE    50000
#define NEDGE    800000
#define KSTEPS   9          // K = 288 = 9*32  (128 src + 128 dst + 32 edge_attr)
#define NFRAG    8          // 128 output cols / 16
#define LDS_KS   7          // K-steps staged in LDS (7*8KB = 57344 B < 64KB)

typedef __attribute__((ext_vector_type(4))) float        f32x4;
typedef __attribute__((ext_vector_type(8))) short        bf16x8;
typedef __attribute__((ext_vector_type(4))) unsigned int u32x4;

#define BPACK_USHORTS  (KSTEPS * NFRAG * 64 * 8)   // 36864 bf16 = 73728 B
#define BIAS_OFF_BYTES (BPACK_USHORTS * 2)         // 73728
#define FLAG_OFF_BYTES (BIAS_OFF_BYTES + 128 * 4)  // 74240
#define NODE_OFF_BYTES 74752                       // 16B-aligned; bf16 nodes, 12.8 MB
#define WS_NEEDED      (NODE_OFF_BYTES + NNODE * HIDDEN * 2)

__device__ __forceinline__ unsigned short f2bf(float f) {
  unsigned u = __builtin_bit_cast(unsigned, f);
  u += 0x7FFFu + ((u >> 16) & 1u);   // RNE
  return (unsigned short)(u >> 16);
}

__device__ __forceinline__ unsigned cvt_pk_bf16(float a, float b) {
  union { __hip_bfloat162 h; unsigned u; } cv;
  cv.h = __float22bfloat162_rn(make_float2(a, b));   // v_cvt_pk_bf16_f32
  return cv.u;
}

__device__ __forceinline__ bf16x8 pack8(f32x4 lo, f32x4 hi) {
  u32x4 u;
  u[0] = cvt_pk_bf16(lo[0], lo[1]);
  u[1] = cvt_pk_bf16(lo[2], lo[3]);
  u[2] = cvt_pk_bf16(hi[0], hi[1]);
  u[3] = cvt_pk_bf16(hi[2], hi[3]);
  return __builtin_bit_cast(bf16x8, u);
}

// ---- setup 1: folded, fragment-packed B (bf16) + effective bias + idx dtype flag
__global__ void setup_kernel(const float* __restrict__ W_edge,
                             const float* __restrict__ b_edge,
                             const float* __restrict__ W1,
                             const float* __restrict__ b1,
                             const void*  __restrict__ eidx,
                             unsigned short* __restrict__ Bpack,
                             float* __restrict__ bias_eff,
                             int*   __restrict__ flag64) {
  const int bid = blockIdx.x, tid = threadIdx.x;
  if (bid < 36) {
    const int pair  = bid * 2 + (tid >> 6);   // 0..71 = kstep*8 + nfrag
    const int lane  = tid & 63;
    const int kstep = pair >> 3;
    const int f     = pair & 7;
    const int col   = f * 16 + (lane & 15);
    const int kbase = kstep * 32 + (lane >> 4) * 8;
    float vals[8];
#pragma unroll
    for (int j = 0; j < 8; ++j) {
      const int k = kbase + j;
      float val;
      if (k < 128) {
        val = W1[k * 128 + col];
      } else if (k < 256) {
        val = W1[(k + 128) * 128 + col];
      } else {
        const int kk = k - 256;
        float s = 0.f;
        for (int t = 0; t < 128; ++t)
          s = fmaf(W_edge[kk * 128 + t], W1[(128 + t) * 128 + col], s);
        val = s;
      }
      vals[j] = val;
    }
    u32x4 sv;
#pragma unroll
    for (int j = 0; j < 4; ++j)
      sv[j] = (unsigned)f2bf(vals[2 * j]) | ((unsigned)f2bf(vals[2 * j + 1]) << 16);
    *(u32x4*)(Bpack + ((kstep * NFRAG + f) * 64 + lane) * 8) = sv;
  } else {
    if (tid < 128) {
      float s = b1[tid];
      for (int t = 0; t < 128; ++t)
        s = fmaf(b_edge[t], W1[(128 + t) * 128 + tid], s);
      bias_eff[tid] = s;
    }
    if (tid == 0) {
      const unsigned* w = (const unsigned*)eidx;
      int all0 = 1;
      for (int i = 0; i < 64; ++i) all0 &= (w[2 * i + 1] == 0u) ? 1 : 0;
      *flag64 = all0;
    }
  }
}

// ---- setup 2: node_features fp32 -> bf16 (row-major, same layout)
__global__ __launch_bounds__(256) void cvt_nodes_kernel(const float* __restrict__ nodef,
                                                        unsigned short* __restrict__ nbf) {
  const int i = blockIdx.x * 256 + threadIdx.x;   // one 8-elem chunk per thread
  if (i >= NNODE * HIDDEN / 8) return;
  f32x4 lo = *(const f32x4*)(nodef + i * 8);
  f32x4 hi = *(const f32x4*)(nodef + i * 8 + 4);
  *(bf16x8*)(nbf + i * 8) = pack8(lo, hi);
}

// ---- main: 512 threads = 8 waves, 32 edges/wave = 256 edges/block.
// B K-steps 0..6 staged in LDS (shared by 8 waves); ks 7..8 read from global (L1-hot).
__global__ __launch_bounds__(512, 4) void edge_attn_kernel(
    const unsigned short* __restrict__ nbf,
    const float* __restrict__ eattr,
    const void*  __restrict__ eidx,
    const unsigned short* __restrict__ Bpack,
    const float* __restrict__ bias_eff,
    const float* __restrict__ W2,
    const float* __restrict__ b2,
    const int*   __restrict__ flag64,
    float* __restrict__ out) {
  __shared__ unsigned short lds_b[LDS_KS * NFRAG * 64 * 8];   // 57344 B

  const int tid   = threadIdx.x;
  const int lane  = tid & 63;
  const int wid   = tid >> 6;                 // 0..7
  const int ebase = blockIdx.x * 256 + wid * 32;
  const int l15   = lane & 15;
  const int kg    = lane >> 4;                // 0..3

  const int e0 = ebase + l15;
  const int e1 = e0 + 16;

  long r0, c0, r1, c1;
  if (*flag64) {
    const long long* p = (const long long*)eidx;
    r0 = (long)p[e0];          r1 = (long)p[e1];
    c0 = (long)p[NEDGE + e0];  c1 = (long)p[NEDGE + e1];
  } else {
    const int* p = (const int*)eidx;
    r0 = p[e0];          r1 = p[e1];
    c0 = p[NEDGE + e0];  c1 = p[NEDGE + e1];
  }

  const unsigned short* ps0 = nbf + (size_t)r0 * HIDDEN + kg * 8;
  const unsigned short* ps1 = nbf + (size_t)r1 * HIDDEN + kg * 8;
  const unsigned short* pd0 = nbf + (size_t)c0 * HIDDEN + kg * 8;
  const unsigned short* pd1 = nbf + (size_t)c1 * HIDDEN + kg * 8;

  // src gathers issued before staging so latency hides under the copy+barrier.
  bf16x8 as0[4], as1[4];
#pragma unroll
  for (int ks = 0; ks < 4; ++ks) {
    as0[ks] = *(const bf16x8*)(ps0 + ks * 32);
    as1[ks] = *(const bf16x8*)(ps1 + ks * 32);
  }

  // Stage B ks 0..6 into LDS: 3584 u32x4, 512 threads x 7.
  {
    const u32x4* s = (const u32x4*)Bpack;
    u32x4*       d = (u32x4*)lds_b;
#pragma unroll
    for (int i = 0; i < LDS_KS; ++i)
      d[tid + i * 512] = s[tid + i * 512];
  }
  __syncthreads();

  f32x4 acc[2][NFRAG];
#pragma unroll
  for (int m = 0; m < 2; ++m)
#pragma unroll
    for (int f = 0; f < NFRAG; ++f)
      acc[m][f] = (f32x4){0.f, 0.f, 0.f, 0.f};

  bf16x8 ad0[4], ad1[4];

  // Phase 1: src rows, K-steps 0..3 (B from LDS). dst gathers issued after ks 0.
#pragma unroll
  for (int ks = 0; ks < 4; ++ks) {
#pragma unroll
    for (int f = 0; f < NFRAG; ++f) {
      bf16x8 bfr = *(const bf16x8*)(lds_b + ((ks * NFRAG + f) * 64 + lane) * 8);
      acc[0][f] = __builtin_amdgcn_mfma_f32_16x16x32_bf16(as0[ks], bfr, acc[0][f], 0, 0, 0);
      acc[1][f] = __builtin_amdgcn_mfma_f32_16x16x32_bf16(as1[ks], bfr, acc[1][f], 0, 0, 0);
    }
    if (ks == 0) {
#pragma unroll
      for (int j = 0; j < 4; ++j) {
        ad0[j] = *(const bf16x8*)(pd0 + j * 32);
        ad1[j] = *(const bf16x8*)(pd1 + j * 32);
      }
    }
  }

  // edge_attr loads (streaming) overlap phase 2.
  const float* pe0 = eattr + (size_t)e0 * EDGE_DIM + kg * 8;
  const float* pe1 = eattr + (size_t)e1 * EDGE_DIM + kg * 8;
  f32x4 ea0lo = *(const f32x4*)(pe0);
  f32x4 ea0hi = *(const f32x4*)(pe0 + 4);
  f32x4 ea1lo = *(const f32x4*)(pe1);
  f32x4 ea1hi = *(const f32x4*)(pe1 + 4);

  // Phase 2: dst rows, K-steps 4..7 (ks 4..6 from LDS, ks 7 from global).
#pragma unroll
  for (int ks = 0; ks < 3; ++ks) {
#pragma unroll
    for (int f = 0; f < NFRAG; ++f) {
      bf16x8 bfr = *(const bf16x8*)(lds_b + (((ks + 4) * NFRAG + f) * 64 + lane) * 8);
      acc[0][f] = __builtin_amdgcn_mfma_f32_16x16x32_bf16(ad0[ks], bfr, acc[0][f], 0, 0, 0);
      acc[1][f] = __builtin_amdgcn_mfma_f32_16x16x32_bf16(ad1[ks], bfr, acc[1][f], 0, 0, 0);
    }
  }
#pragma unroll
  for (int f = 0; f < NFRAG; ++f) {
    bf16x8 bfr = *(const bf16x8*)(Bpack + ((7 * NFRAG + f) * 64 + lane) * 8);
    acc[0][f] = __builtin_amdgcn_mfma_f32_16x16x32_bf16(ad0[3], bfr, acc[0][f], 0, 0, 0);
    acc[1][f] = __builtin_amdgcn_mfma_f32_16x16x32_bf16(ad1[3], bfr, acc[1][f], 0, 0, 0);
  }

  // Phase 3: edge_attr, K-step 8 (B from global, L1-hot).
  {
    bf16x8 ae0 = pack8(ea0lo, ea0hi);
    bf16x8 ae1 = pack8(ea1lo, ea1hi);
#pragma unroll
    for (int f = 0; f < NFRAG; ++f) {
      bf16x8 bfr = *(const bf16x8*)(Bpack + ((8 * NFRAG + f) * 64 + lane) * 8);
      acc[0][f] = __builtin_amdgcn_mfma_f32_16x16x32_bf16(ae0, bfr, acc[0][f], 0, 0, 0);
      acc[1][f] = __builtin_amdgcn_mfma_f32_16x16x32_bf16(ae1, bfr, acc[1][f], 0, 0, 0);
    }
  }

  // Epilogue: bias + ReLU + dot(W2) in registers, 16-lane xor-reduce, sigmoid.
  float w2v[NFRAG], bv[NFRAG];
#pragma unroll
  for (int f = 0; f < NFRAG; ++f) {
    w2v[f] = W2[f * 16 + l15];
    bv[f]  = bias_eff[f * 16 + l15];
  }
  const float bias2 = b2[0];

  float part[2][4];
#pragma unroll
  for (int m = 0; m < 2; ++m)
#pragma unroll
    for (int r = 0; r < 4; ++r) {
      float s = 0.f;
#pragma unroll
      for (int f = 0; f < NFRAG; ++f) {
        float h = acc[m][f][r] + bv[f];
        h = fmaxf(h, 0.f);
        s = fmaf(h, w2v[f], s);
      }
      part[m][r] = s;
    }

#pragma unroll
  for (int mask = 1; mask < 16; mask <<= 1) {
#pragma unroll
    for (int m = 0; m < 2; ++m)
#pragma unroll
      for (int r = 0; r < 4; ++r)
        part[m][r] += __shfl_xor(part[m][r], mask, 64);
  }

  if (l15 == 0) {
#pragma unroll
    for (int m = 0; m < 2; ++m)
#pragma unroll
      for (int r = 0; r < 4; ++r) {
        float x = part[m][r] + bias2;
        out[ebase + m * 16 + kg * 4 + r] = 1.f / (1.f + __expf(-x));
      }
  }
}

// ---- fallback main (round-1 style, fp32 gathers) in case ws is too small for bf16 nodes
__global__ __launch_bounds__(256) void edge_attn_kernel_fp32(
    const float* __restrict__ nodef,
    const float* __restrict__ eattr,
    const void*  __restrict__ eidx,
    const unsigned short* __restrict__ Bpack,
    const float* __restrict__ bias_eff,
    const float* __restrict__ W2,
    const float* __restrict__ b2,
    const int*   __restrict__ flag64,
    float* __restrict__ out) {
  const int lane  = threadIdx.x & 63;
  const int wid   = threadIdx.x >> 6;
  const int ebase = blockIdx.x * 128 + wid * 32;
  const int l15   = lane & 15;
  const int kg    = lane >> 4;
  const int koff  = kg * 8;
  const int e0 = ebase + l15;
  const int e1 = e0 + 16;

  long r0, c0, r1, c1;
  if (*flag64) {
    const long long* p = (const long long*)eidx;
    r0 = (long)p[e0];          r1 = (long)p[e1];
    c0 = (long)p[NEDGE + e0];  c1 = (long)p[NEDGE + e1];
  } else {
    const int* p = (const int*)eidx;
    r0 = p[e0];          r1 = p[e1];
    c0 = p[NEDGE + e0];  c1 = p[NEDGE + e1];
  }

  f32x4 acc[2][NFRAG];
#pragma unroll
  for (int m = 0; m < 2; ++m)
#pragma unroll
    for (int f = 0; f < NFRAG; ++f)
      acc[m][f] = (f32x4){0.f, 0.f, 0.f, 0.f};

#pragma unroll 1
  for (int ks = 0; ks < KSTEPS; ++ks) {
    const float *p0, *p1;
    if (ks < 4)      { p0 = nodef + r0 * HIDDEN + ks * 32;       p1 = nodef + r1 * HIDDEN + ks * 32; }
    else if (ks < 8) { p0 = nodef + c0 * HIDDEN + (ks - 4) * 32; p1 = nodef + c1 * HIDDEN + (ks - 4) * 32; }
    else             { p0 = eattr + (long)e0 * EDGE_DIM;         p1 = eattr + (long)e1 * EDGE_DIM; }

    f32x4 lo0 = *(const f32x4*)(p0 + koff);
    f32x4 hi0 = *(const f32x4*)(p0 + koff + 4);
    f32x4 lo1 = *(const f32x4*)(p1 + koff);
    f32x4 hi1 = *(const f32x4*)(p1 + koff + 4);
    bf16x8 a0 = pack8(lo0, hi0);
    bf16x8 a1 = pack8(lo1, hi1);

#pragma unroll
    for (int f = 0; f < NFRAG; ++f) {
      bf16x8 bfr = *(const bf16x8*)(Bpack + ((ks * NFRAG + f) * 64 + lane) * 8);
      acc[0][f] = __builtin_amdgcn_mfma_f32_16x16x32_bf16(a0, bfr, acc[0][f], 0, 0, 0);
      acc[1][f] = __builtin_amdgcn_mfma_f32_16x16x32_bf16(a1, bfr, acc[1][f], 0, 0, 0);
    }
  }

  float w2v[NFRAG], bv[NFRAG];
#pragma unroll
  for (int f = 0; f < NFRAG; ++f) {
    w2v[f] = W2[f * 16 + l15];
    bv[f]  = bias_eff[f * 16 + l15];
  }
  const float bias2 = b2[0];

  float part[2][4];
#pragma unroll
  for (int m = 0; m < 2; ++m)
#pragma unroll
    for (int r = 0; r < 4; ++r) {
      float s = 0.f;
#pragma unroll
      for (int f = 0; f < NFRAG; ++f) {
        float h = acc[m][f][r] + bv[f];
        h = fmaxf(h, 0.f);
        s = fmaf(h, w2v[f], s);
      }
      part[m][r] = s;
    }

#pragma unroll
  for (int mask = 1; mask < 16; mask <<= 1) {
#pragma unroll
    for (int m = 0; m < 2; ++m)
#pragma unroll
      for (int r = 0; r < 4; ++r)
        part[m][r] += __shfl_xor(part[m][r], mask, 64);
  }

  if (l15 == 0) {
#pragma unroll
    for (int m = 0; m < 2; ++m)
#pragma unroll
      for (int r = 0; r < 4; ++r) {
        float x = part[m][r] + bias2;
        out[ebase + m * 16 + kg * 4 + r] = 1.f / (1.f + __expf(-x));
      }
  }
}

extern "C" void kernel_launch(void* const* d_in, const int* in_sizes, int n_in,
                              void* d_out, int out_size, void* d_ws, size_t ws_size,
                              hipStream_t stream) {
  const float* nodef  = (const float*)d_in[0];
  const float* eattr  = (const float*)d_in[1];
  const float* W_edge = (const float*)d_in[2];
  const float* b_edge = (const float*)d_in[3];
  const float* W1     = (const float*)d_in[4];
  const float* b1     = (const float*)d_in[5];
  const float* W2     = (const float*)d_in[6];
  const float* b2     = (const float*)d_in[7];
  const void*  eidx   = d_in[8];

  unsigned short* Bpack    = (unsigned short*)d_ws;
  float*          bias_eff = (float*)((char*)d_ws + BIAS_OFF_BYTES);
  int*            flag64   = (int*)((char*)d_ws + FLAG_OFF_BYTES);
  unsigned short* nbf      = (unsigned short*)((char*)d_ws + NODE_OFF_BYTES);

  setup_kernel<<<dim3(37), dim3(128), 0, stream>>>(W_edge, b_edge, W1, b1, eidx,
                                                   Bpack, bias_eff, flag64);

  if (ws_size >= (size_t)WS_NEEDED) {
    cvt_nodes_kernel<<<dim3((NNODE * HIDDEN / 8 + 255) / 256), dim3(256), 0, stream>>>(nodef, nbf);
    edge_attn_kernel<<<dim3(NEDGE / 256), dim3(512), 0, stream>>>(
        nbf, eattr, eidx, Bpack, bias_eff, W2, b2, flag64, (float*)d_out);
  } else {
    edge_attn_kernel_fp32<<<dim3(NEDGE / 128), dim3(256), 0, stream>>>(
        nodef, eattr, eidx, Bpack, bias_eff, W2, b2, flag64, (float*)d_out);
  }
}

// Round 4
// 129.410 us; speedup vs baseline: 1.6375x; 1.2015x over previous
//
#include <hip/hip_runtime.h>
#include <hip/hip_bf16.h>

#define HIDDEN   128
#define EDGE_DIM 32
#define NNODE    50000
#define NEDGE    800000
#define KSTEPS   9          // K = 288 = 9*32  (128 src + 128 dst + 32 edge_attr)
#define NFRAG    8          // 128 output cols / 16
#define LDS_KS   8          // K-steps staged in LDS (8*8KB = 65536 B, static max)

typedef __attribute__((ext_vector_type(4))) float        f32x4;
typedef __attribute__((ext_vector_type(8))) short        bf16x8;
typedef __attribute__((ext_vector_type(4))) unsigned int u32x4;

#define BPACK_USHORTS  (KSTEPS * NFRAG * 64 * 8)   // 36864 bf16 = 73728 B
#define BIAS_OFF_BYTES (BPACK_USHORTS * 2)         // 73728
#define FLAG_OFF_BYTES (BIAS_OFF_BYTES + 128 * 4)  // 74240
#define NODE_OFF_BYTES 74752                       // 16B-aligned; bf16 nodes, 12.8 MB
#define WS_NEEDED      (NODE_OFF_BYTES + NNODE * HIDDEN * 2)

__device__ __forceinline__ unsigned short f2bf(float f) {
  unsigned u = __builtin_bit_cast(unsigned, f);
  u += 0x7FFFu + ((u >> 16) & 1u);   // RNE
  return (unsigned short)(u >> 16);
}

__device__ __forceinline__ unsigned cvt_pk_bf16(float a, float b) {
  union { __hip_bfloat162 h; unsigned u; } cv;
  cv.h = __float22bfloat162_rn(make_float2(a, b));   // v_cvt_pk_bf16_f32
  return cv.u;
}

__device__ __forceinline__ bf16x8 pack8(f32x4 lo, f32x4 hi) {
  u32x4 u;
  u[0] = cvt_pk_bf16(lo[0], lo[1]);
  u[1] = cvt_pk_bf16(lo[2], lo[3]);
  u[2] = cvt_pk_bf16(hi[0], hi[1]);
  u[3] = cvt_pk_bf16(hi[2], hi[3]);
  return __builtin_bit_cast(bf16x8, u);
}

// async global->LDS, 16B per lane, LDS dest = wave-uniform base + lane*16
__device__ __forceinline__ void gload_lds16(const void* g, void* l) {
  __builtin_amdgcn_global_load_lds(
      (const __attribute__((address_space(1))) unsigned int*)g,
      (__attribute__((address_space(3))) unsigned int*)l, 16, 0, 0);
}

// ---- setup 1: folded, fragment-packed B (bf16) + effective bias + idx dtype flag
__global__ void setup_kernel(const float* __restrict__ W_edge,
                             const float* __restrict__ b_edge,
                             const float* __restrict__ W1,
                             const float* __restrict__ b1,
                             const void*  __restrict__ eidx,
                             unsigned short* __restrict__ Bpack,
                             float* __restrict__ bias_eff,
                             int*   __restrict__ flag64) {
  const int bid = blockIdx.x, tid = threadIdx.x;
  if (bid < 36) {
    const int pair  = bid * 2 + (tid >> 6);   // 0..71 = kstep*8 + nfrag
    const int lane  = tid & 63;
    const int kstep = pair >> 3;
    const int f     = pair & 7;
    const int col   = f * 16 + (lane & 15);
    const int kbase = kstep * 32 + (lane >> 4) * 8;
    float vals[8];
#pragma unroll
    for (int j = 0; j < 8; ++j) {
      const int k = kbase + j;
      float val;
      if (k < 128) {
        val = W1[k * 128 + col];
      } else if (k < 256) {
        val = W1[(k + 128) * 128 + col];
      } else {
        const int kk = k - 256;
        float s = 0.f;
        for (int t = 0; t < 128; ++t)
          s = fmaf(W_edge[kk * 128 + t], W1[(128 + t) * 128 + col], s);
        val = s;
      }
      vals[j] = val;
    }
    u32x4 sv;
#pragma unroll
    for (int j = 0; j < 4; ++j)
      sv[j] = (unsigned)f2bf(vals[2 * j]) | ((unsigned)f2bf(vals[2 * j + 1]) << 16);
    *(u32x4*)(Bpack + ((kstep * NFRAG + f) * 64 + lane) * 8) = sv;
  } else {
    if (tid < 128) {
      float s = b1[tid];
      for (int t = 0; t < 128; ++t)
        s = fmaf(b_edge[t], W1[(128 + t) * 128 + tid], s);
      bias_eff[tid] = s;
    }
    if (tid == 0) {
      const unsigned* w = (const unsigned*)eidx;
      int all0 = 1;
      for (int i = 0; i < 64; ++i) all0 &= (w[2 * i + 1] == 0u) ? 1 : 0;
      *flag64 = all0;
    }
  }
}

// ---- setup 2: node_features fp32 -> bf16 (row-major, same layout)
__global__ __launch_bounds__(256) void cvt_nodes_kernel(const float* __restrict__ nodef,
                                                        unsigned short* __restrict__ nbf) {
  const int i = blockIdx.x * 256 + threadIdx.x;   // one 8-elem chunk per thread
  if (i >= NNODE * HIDDEN / 8) return;
  f32x4 lo = *(const f32x4*)(nodef + i * 8);
  f32x4 hi = *(const f32x4*)(nodef + i * 8 + 4);
  *(bf16x8*)(nbf + i * 8) = pack8(lo, hi);
}

// ---- main: 256 threads = 4 waves, 32 edges/wave = 128 edges/block.
// All VMEM (eidx, gathers, eattr, ks8-B, W2/bias) issued pre-barrier; B ks0..7
// staged to LDS via global_load_lds. Post-barrier: pure LDS + MFMA + epilogue.
__global__ __launch_bounds__(256, 2) void edge_attn_kernel(
    const unsigned short* __restrict__ nbf,
    const float* __restrict__ eattr,
    const void*  __restrict__ eidx,
    const unsigned short* __restrict__ Bpack,
    const float* __restrict__ bias_eff,
    const float* __restrict__ W2,
    const float* __restrict__ b2,
    const int*   __restrict__ flag64,
    float* __restrict__ out) {
  __shared__ unsigned short lds_b[LDS_KS * NFRAG * 64 * 8];   // 65536 B

  const int tid   = threadIdx.x;
  const int lane  = tid & 63;
  const int wid   = tid >> 6;                 // 0..3
  const int ebase = blockIdx.x * 128 + wid * 32;
  const int l15   = lane & 15;
  const int kg    = lane >> 4;                // 0..3

  const int e0 = ebase + l15;
  const int e1 = e0 + 16;

  long r0, c0, r1, c1;
  if (*flag64) {
    const long long* p = (const long long*)eidx;
    r0 = (long)p[e0];          r1 = (long)p[e1];
    c0 = (long)p[NEDGE + e0];  c1 = (long)p[NEDGE + e1];
  } else {
    const int* p = (const int*)eidx;
    r0 = p[e0];          r1 = p[e1];
    c0 = p[NEDGE + e0];  c1 = p[NEDGE + e1];
  }

  // ---- pre-barrier load phase: issue EVERYTHING ----
  // edge_attr first (HBM, longest latency)
  const float* pe0 = eattr + (size_t)e0 * EDGE_DIM + kg * 8;
  const float* pe1 = eattr + (size_t)e1 * EDGE_DIM + kg * 8;
  f32x4 ea0lo = *(const f32x4*)(pe0);
  f32x4 ea0hi = *(const f32x4*)(pe0 + 4);
  f32x4 ea1lo = *(const f32x4*)(pe1);
  f32x4 ea1hi = *(const f32x4*)(pe1 + 4);

  // node gathers (L2/L3)
  const unsigned short* ps0 = nbf + (size_t)r0 * HIDDEN + kg * 8;
  const unsigned short* ps1 = nbf + (size_t)r1 * HIDDEN + kg * 8;
  const unsigned short* pd0 = nbf + (size_t)c0 * HIDDEN + kg * 8;
  const unsigned short* pd1 = nbf + (size_t)c1 * HIDDEN + kg * 8;
  bf16x8 as0[4], as1[4], ad0[4], ad1[4];
#pragma unroll
  for (int ks = 0; ks < 4; ++ks) {
    as0[ks] = *(const bf16x8*)(ps0 + ks * 32);
    as1[ks] = *(const bf16x8*)(ps1 + ks * 32);
    ad0[ks] = *(const bf16x8*)(pd0 + ks * 32);
    ad1[ks] = *(const bf16x8*)(pd1 + ks * 32);
  }

  // ks8 B-fragments to registers (L2-hot, shared by all waves)
  bf16x8 bfr8[NFRAG];
#pragma unroll
  for (int f = 0; f < NFRAG; ++f)
    bfr8[f] = *(const bf16x8*)(Bpack + ((8 * NFRAG + f) * 64 + lane) * 8);

  // epilogue weights
  float w2v[NFRAG], bv[NFRAG];
#pragma unroll
  for (int f = 0; f < NFRAG; ++f) {
    w2v[f] = W2[f * 16 + l15];
    bv[f]  = bias_eff[f * 16 + l15];
  }
  const float bias2 = b2[0];

  // stage B ks0..7 into LDS: 4096 16B-chunks, 16 rounds of 256 threads
#pragma unroll
  for (int i = 0; i < 16; ++i) {
    const char* g = (const char*)Bpack + (size_t)(i * 256 + tid) * 16;
    char*       l = (char*)lds_b + (size_t)(i * 256 + wid * 64) * 16;
    gload_lds16(g, l);
  }
  __syncthreads();   // drains vmcnt (incl. global_load_lds) + lgkmcnt

  // ---- compute phase: no VMEM until the output store ----
  f32x4 acc[2][NFRAG];
#pragma unroll
  for (int m = 0; m < 2; ++m)
#pragma unroll
    for (int f = 0; f < NFRAG; ++f)
      acc[m][f] = (f32x4){bv[f], bv[f], bv[f], bv[f]};   // bias folded into init

#pragma unroll
  for (int ks = 0; ks < 4; ++ks) {
#pragma unroll
    for (int f = 0; f < NFRAG; ++f) {
      bf16x8 bfr = *(const bf16x8*)(lds_b + ((ks * NFRAG + f) * 64 + lane) * 8);
      acc[0][f] = __builtin_amdgcn_mfma_f32_16x16x32_bf16(as0[ks], bfr, acc[0][f], 0, 0, 0);
      acc[1][f] = __builtin_amdgcn_mfma_f32_16x16x32_bf16(as1[ks], bfr, acc[1][f], 0, 0, 0);
    }
  }
#pragma unroll
  for (int ks = 0; ks < 4; ++ks) {
#pragma unroll
    for (int f = 0; f < NFRAG; ++f) {
      bf16x8 bfr = *(const bf16x8*)(lds_b + (((ks + 4) * NFRAG + f) * 64 + lane) * 8);
      acc[0][f] = __builtin_amdgcn_mfma_f32_16x16x32_bf16(ad0[ks], bfr, acc[0][f], 0, 0, 0);
      acc[1][f] = __builtin_amdgcn_mfma_f32_16x16x32_bf16(ad1[ks], bfr, acc[1][f], 0, 0, 0);
    }
  }
  {
    bf16x8 ae0 = pack8(ea0lo, ea0hi);
    bf16x8 ae1 = pack8(ea1lo, ea1hi);
#pragma unroll
    for (int f = 0; f < NFRAG; ++f) {
      acc[0][f] = __builtin_amdgcn_mfma_f32_16x16x32_bf16(ae0, bfr8[f], acc[0][f], 0, 0, 0);
      acc[1][f] = __builtin_amdgcn_mfma_f32_16x16x32_bf16(ae1, bfr8[f], acc[1][f], 0, 0, 0);
    }
  }

  // Epilogue: ReLU + dot(W2) in registers, 16-lane xor-reduce, sigmoid.
  float part[2][4];
#pragma unroll
  for (int m = 0; m < 2; ++m)
#pragma unroll
    for (int r = 0; r < 4; ++r) {
      float s = 0.f;
#pragma unroll
      for (int f = 0; f < NFRAG; ++f) {
        float h = fmaxf(acc[m][f][r], 0.f);
        s = fmaf(h, w2v[f], s);
      }
      part[m][r] = s;
    }

#pragma unroll
  for (int mask = 1; mask < 16; mask <<= 1) {
#pragma unroll
    for (int m = 0; m < 2; ++m)
#pragma unroll
      for (int r = 0; r < 4; ++r)
        part[m][r] += __shfl_xor(part[m][r], mask, 64);
  }

  if (l15 == 0) {
#pragma unroll
    for (int m = 0; m < 2; ++m)
#pragma unroll
      for (int r = 0; r < 4; ++r) {
        float x = part[m][r] + bias2;
        out[ebase + m * 16 + kg * 4 + r] = 1.f / (1.f + __expf(-x));
      }
  }
}

// ---- fallback main (round-1 style, fp32 gathers) in case ws is too small for bf16 nodes
__global__ __launch_bounds__(256) void edge_attn_kernel_fp32(
    const float* __restrict__ nodef,
    const float* __restrict__ eattr,
    const void*  __restrict__ eidx,
    const unsigned short* __restrict__ Bpack,
    const float* __restrict__ bias_eff,
    const float* __restrict__ W2,
    const float* __restrict__ b2,
    const int*   __restrict__ flag64,
    float* __restrict__ out) {
  const int lane  = threadIdx.x & 63;
  const int wid   = threadIdx.x >> 6;
  const int ebase = blockIdx.x * 128 + wid * 32;
  const int l15   = lane & 15;
  const int kg    = lane >> 4;
  const int koff  = kg * 8;
  const int e0 = ebase + l15;
  const int e1 = e0 + 16;

  long r0, c0, r1, c1;
  if (*flag64) {
    const long long* p = (const long long*)eidx;
    r0 = (long)p[e0];          r1 = (long)p[e1];
    c0 = (long)p[NEDGE + e0];  c1 = (long)p[NEDGE + e1];
  } else {
    const int* p = (const int*)eidx;
    r0 = p[e0];          r1 = p[e1];
    c0 = p[NEDGE + e0];  c1 = p[NEDGE + e1];
  }

  f32x4 acc[2][NFRAG];
#pragma unroll
  for (int m = 0; m < 2; ++m)
#pragma unroll
    for (int f = 0; f < NFRAG; ++f)
      acc[m][f] = (f32x4){0.f, 0.f, 0.f, 0.f};

#pragma unroll 1
  for (int ks = 0; ks < KSTEPS; ++ks) {
    const float *p0, *p1;
    if (ks < 4)      { p0 = nodef + r0 * HIDDEN + ks * 32;       p1 = nodef + r1 * HIDDEN + ks * 32; }
    else if (ks < 8) { p0 = nodef + c0 * HIDDEN + (ks - 4) * 32; p1 = nodef + c1 * HIDDEN + (ks - 4) * 32; }
    else             { p0 = eattr + (long)e0 * EDGE_DIM;         p1 = eattr + (long)e1 * EDGE_DIM; }

    f32x4 lo0 = *(const f32x4*)(p0 + koff);
    f32x4 hi0 = *(const f32x4*)(p0 + koff + 4);
    f32x4 lo1 = *(const f32x4*)(p1 + koff);
    f32x4 hi1 = *(const f32x4*)(p1 + koff + 4);
    bf16x8 a0 = pack8(lo0, hi0);
    bf16x8 a1 = pack8(lo1, hi1);

#pragma unroll
    for (int f = 0; f < NFRAG; ++f) {
      bf16x8 bfr = *(const bf16x8*)(Bpack + ((ks * NFRAG + f) * 64 + lane) * 8);
      acc[0][f] = __builtin_amdgcn_mfma_f32_16x16x32_bf16(a0, bfr, acc[0][f], 0, 0, 0);
      acc[1][f] = __builtin_amdgcn_mfma_f32_16x16x32_bf16(a1, bfr, acc[1][f], 0, 0, 0);
    }
  }

  float w2v[NFRAG], bv[NFRAG];
#pragma unroll
  for (int f = 0; f < NFRAG; ++f) {
    w2v[f] = W2[f * 16 + l15];
    bv[f]  = bias_eff[f * 16 + l15];
  }
  const float bias2 = b2[0];

  float part[2][4];
#pragma unroll
  for (int m = 0; m < 2; ++m)
#pragma unroll
    for (int r = 0; r < 4; ++r) {
      float s = 0.f;
#pragma unroll
      for (int f = 0; f < NFRAG; ++f) {
        float h = acc[m][f][r] + bv[f];
        h = fmaxf(h, 0.f);
        s = fmaf(h, w2v[f], s);
      }
      part[m][r] = s;
    }

#pragma unroll
  for (int mask = 1; mask < 16; mask <<= 1) {
#pragma unroll
    for (int m = 0; m < 2; ++m)
#pragma unroll
      for (int r = 0; r < 4; ++r)
        part[m][r] += __shfl_xor(part[m][r], mask, 64);
  }

  if (l15 == 0) {
#pragma unroll
    for (int m = 0; m < 2; ++m)
#pragma unroll
      for (int r = 0; r < 4; ++r) {
        float x = part[m][r] + bias2;
        out[ebase + m * 16 + kg * 4 + r] = 1.f / (1.f + __expf(-x));
      }
  }
}

extern "C" void kernel_launch(void* const* d_in, const int* in_sizes, int n_in,
                              void* d_out, int out_size, void* d_ws, size_t ws_size,
                              hipStream_t stream) {
  const float* nodef  = (const float*)d_in[0];
  const float* eattr  = (const float*)d_in[1];
  const float* W_edge = (const float*)d_in[2];
  const float* b_edge = (const float*)d_in[3];
  const float* W1     = (const float*)d_in[4];
  const float* b1     = (const float*)d_in[5];
  const float* W2     = (const float*)d_in[6];
  const float* b2     = (const float*)d_in[7];
  const void*  eidx   = d_in[8];

  unsigned short* Bpack    = (unsigned short*)d_ws;
  float*          bias_eff = (float*)((char*)d_ws + BIAS_OFF_BYTES);
  int*            flag64   = (int*)((char*)d_ws + FLAG_OFF_BYTES);
  unsigned short* nbf      = (unsigned short*)((char*)d_ws + NODE_OFF_BYTES);

  setup_kernel<<<dim3(37), dim3(128), 0, stream>>>(W_edge, b_edge, W1, b1, eidx,
                                                   Bpack, bias_eff, flag64);

  if (ws_size >= (size_t)WS_NEEDED) {
    cvt_nodes_kernel<<<dim3((NNODE * HIDDEN / 8 + 255) / 256), dim3(256), 0, stream>>>(nodef, nbf);
    edge_attn_kernel<<<dim3(NEDGE / 128), dim3(256), 0, stream>>>(
        nbf, eattr, eidx, Bpack, bias_eff, W2, b2, flag64, (float*)d_out);
  } else {
    edge_attn_kernel_fp32<<<dim3(NEDGE / 128), dim3(256), 0, stream>>>(
        nodef, eattr, eidx, Bpack, bias_eff, W2, b2, flag64, (float*)d_out);
  }
}